// Round 1
// 1005.035 us; speedup vs baseline: 1.0471x; 1.0471x over previous
//
#include <hip/hip_runtime.h>
#include <cstdint>

#define NEG_SLOPE 0.2f

typedef __attribute__((ext_vector_type(8))) short short8;     // 8 bf16 = 4 VGPRs
typedef __attribute__((ext_vector_type(8))) unsigned short ushort8;
typedef __attribute__((ext_vector_type(4))) float f32x4;
typedef __attribute__((ext_vector_type(2))) float f32x2;
typedef __attribute__((ext_vector_type(4))) unsigned short ushort4v;

// split fp32 v into bf16 hi + bf16 lo (truncation; hi+lo ~ v to ~2^-16 rel)
__device__ inline void split_bf16(float v, short& hi, short& lo) {
  unsigned u = __builtin_bit_cast(unsigned, v);
  hi = (short)(u >> 16);
  float hif = __builtin_bit_cast(float, u & 0xffff0000u);
  float r = v - hif;
  lo = (short)(__builtin_bit_cast(unsigned, r) >> 16);
}

__device__ inline float b2f(unsigned short u) {
  return __builtin_bit_cast(float, (unsigned)u << 16);
}
__device__ inline unsigned short f2b_rne(float f) {
  unsigned u = __builtin_bit_cast(unsigned, f);
  return (unsigned short)((u + 0x7fffu + ((u >> 16) & 1u)) >> 16);
}
__device__ inline float leaky(float e) { return e > 0.f ? e : NEG_SLOPE * e; }

// ---------------- CSR build ----------------

__global__ __launch_bounds__(256) void hist_kernel(const int* __restrict__ ei,
                                                   int* __restrict__ deg, int E, int N) {
  int e = blockIdx.x * 256 + threadIdx.x;
  int total = E + N;
  if (e >= total) return;
  int d = (e < E) ? ei[E + e] : (e - E);   // self-loop for virtual edges
  atomicAdd(&deg[d], 1);
}

// ---- 3-phase device-wide exclusive scan of deg[0..n) (chunk=1024/block; n<=262144) ----

__global__ __launch_bounds__(256) void scan_phaseA(const int* __restrict__ deg,
                                                   int* __restrict__ bsum, int n) {
  __shared__ int red[256];
  int base = blockIdx.x * 1024;
  int s = 0;
#pragma unroll
  for (int j = 0; j < 4; j++) {
    int i = base + threadIdx.x + j * 256;
    if (i < n) s += deg[i];
  }
  red[threadIdx.x] = s;
  __syncthreads();
  for (int off = 128; off; off >>= 1) {
    if (threadIdx.x < off) red[threadIdx.x] += red[threadIdx.x + off];
    __syncthreads();
  }
  if (threadIdx.x == 0) bsum[blockIdx.x] = red[0];
}

__global__ __launch_bounds__(256) void scan_phaseB(int* __restrict__ bsum,
                                                   int* __restrict__ rowstart,
                                                   int nb, int n) {
  __shared__ int sc[256];
  int tid = threadIdx.x;
  int v = (tid < nb) ? bsum[tid] : 0;
  sc[tid] = v;
  __syncthreads();
  for (int off = 1; off < 256; off <<= 1) {
    int t = (tid >= off) ? sc[tid - off] : 0;
    __syncthreads();
    sc[tid] += t;
    __syncthreads();
  }
  if (tid < nb) bsum[tid] = sc[tid] - v;   // exclusive block offsets
  if (tid == 0) rowstart[n] = sc[255];     // grand total
}

__global__ __launch_bounds__(256) void scan_phaseC(const int* __restrict__ deg,
                                                   const int* __restrict__ bsum,
                                                   int* __restrict__ rowstart,
                                                   int* __restrict__ cursor, int n) {
  __shared__ int tsum[256];
  int tid = threadIdx.x;
  int base = blockIdx.x * 1024 + tid * 4;  // 4 contiguous per thread
  int d[4];
  int s = 0;
#pragma unroll
  for (int j = 0; j < 4; j++) {
    int i = base + j;
    d[j] = (i < n) ? deg[i] : 0;
    s += d[j];
  }
  tsum[tid] = s;
  __syncthreads();
  for (int off = 1; off < 256; off <<= 1) {
    int t = (tid >= off) ? tsum[tid - off] : 0;
    __syncthreads();
    tsum[tid] += t;
    __syncthreads();
  }
  int run = bsum[blockIdx.x] + tsum[tid] - s;  // exclusive prefix for this thread
#pragma unroll
  for (int j = 0; j < 4; j++) {
    int i = base + j;
    if (i < n) { rowstart[i] = run; cursor[i] = run; }
    run += d[j];
  }
}

__global__ __launch_bounds__(256) void scatter_kernel(const int* __restrict__ ei,
                                                      int* __restrict__ cursor,
                                                      int* __restrict__ csr_src, int E, int N) {
  int e = blockIdx.x * 256 + threadIdx.x;
  int total = E + N;
  if (e >= total) return;
  int s, d;
  if (e < E) { s = ei[e]; d = ei[E + e]; }
  else       { s = e - E; d = e - E; }
  int p = atomicAdd(&cursor[d], 1);
  csr_src[p] = s;
}

// ---------------- weight convert: W[K][N] fp32 -> Wt_hi/Wt_lo [N][Kp] bf16, zero-pad ----

__global__ __launch_bounds__(256) void convw_kernel(const float* __restrict__ W,
                                                    short* __restrict__ Whi,
                                                    short* __restrict__ Wlo,
                                                    int K, int N, int Kp) {
  int idx = blockIdx.x * 256 + threadIdx.x;
  if (idx >= N * Kp) return;
  int n = idx / Kp, k = idx % Kp;
  float v = (k < K) ? W[(size_t)k * N + n] : 0.f;
  short hi, lo;
  split_bf16(v, hi, lo);
  Whi[idx] = hi;
  Wlo[idx] = lo;
}

// ---------------- 2-stream MFMA GEMM: C = round_bf16(A) @ (Bhi+Blo)^T ----------------
// A fp32 (rounded RNE in staging) or pre-rounded bf16 (ABF16 path: pure copy staging).
// B pre-split hi+lo keeps weight precision. 32 MFMAs/tile, 3 LDS buffers (~31 KB).

#define LDK 40   // padded LDS k-stride: 80B rows -> uniform 2-way bank aliasing (free, m136)

template <bool ABF16>
__global__ __launch_bounds__(256, 3) void mfma_gemm_split(
    const float* __restrict__ Af, const short* __restrict__ Ab,
    const short* __restrict__ Bhi, const short* __restrict__ Blo,
    unsigned short* __restrict__ C, int M, int Nn, int K, int Kp) {
  __shared__ short Ah[128 * LDK], Bh[128 * LDK], Bl[128 * LDK];

  const int t = threadIdx.x;
  const int bm = blockIdx.x * 128;
  const int n0 = blockIdx.y * 128;

  const int srow = t >> 1;        // staging row 0..127
  const int shalf = t & 1;        // which 16-elem half of the 32-k tile
  const bool arow_ok = (bm + srow) < M;

  const int w = t >> 6, lane = t & 63;
  const int wm = (w >> 1) * 64, wn = (w & 1) * 64;  // wave's 64x64 quadrant
  const int lm = lane & 15, quad = lane >> 4;

  f32x4 acc[4][4];
#pragma unroll
  for (int i = 0; i < 4; i++)
#pragma unroll
    for (int j = 0; j < 4; j++) acc[i][j] = (f32x4)(0.f);

  for (int k0 = 0; k0 < Kp; k0 += 32) {
    __syncthreads();

    // --- stage A ---
    if constexpr (ABF16) {
      const int kbase = k0 + shalf * 16;
      short8 v0 = (short8)0, v1 = (short8)0;
      if (arow_ok && kbase < K) {
        const short8* p = (const short8*)(Ab + (size_t)(bm + srow) * Kp + kbase);
        v0 = p[0]; v1 = p[1];
      }
      const int la = srow * LDK + shalf * 16;
      *(short8*)&Ah[la] = v0;
      *(short8*)&Ah[la + 8] = v1;
    } else {
      const int kbase = k0 + shalf * 16;
      f32x4 v0 = (f32x4)(0.f), v1 = (f32x4)(0.f), v2 = (f32x4)(0.f), v3 = (f32x4)(0.f);
      if (arow_ok && kbase < K) {   // K % 16 == 0 -> chunk fully in or out
        const f32x4* p = (const f32x4*)(Af + (size_t)(bm + srow) * K + kbase);
        v0 = p[0]; v1 = p[1]; v2 = p[2]; v3 = p[3];
      }
      float f[16] = {v0[0], v0[1], v0[2], v0[3], v1[0], v1[1], v1[2], v1[3],
                     v2[0], v2[1], v2[2], v2[3], v3[0], v3[1], v3[2], v3[3]};
      unsigned short hi[16];
#pragma unroll
      for (int j = 0; j < 16; j++) hi[j] = f2b_rne(f[j]);
      const int la = srow * LDK + shalf * 16;
      *(short8*)&Ah[la] = *(short8*)&hi[0];
      *(short8*)&Ah[la + 8] = *(short8*)&hi[8];
    }
    // --- stage B ---
    {
      const size_t gb = (size_t)(n0 + srow) * Kp + k0 + shalf * 16;
      const short8* ph = (const short8*)(Bhi + gb);
      const short8* pl = (const short8*)(Blo + gb);
      short8 h0 = ph[0], h1 = ph[1], l0 = pl[0], l1 = pl[1];
      const int la = srow * LDK + shalf * 16;
      *(short8*)&Bh[la] = h0;
      *(short8*)&Bh[la + 8] = h1;
      *(short8*)&Bl[la] = l0;
      *(short8*)&Bl[la + 8] = l1;
    }
    __syncthreads();

    // --- fragments + 32 MFMAs ---
    short8 afh[4], bfh[4], bfl[4];
#pragma unroll
    for (int i = 0; i < 4; i++) {
      const int ra = (wm + i * 16 + lm) * LDK + quad * 8;
      afh[i] = *(const short8*)&Ah[ra];
      const int rb = (wn + i * 16 + lm) * LDK + quad * 8;
      bfh[i] = *(const short8*)&Bh[rb];
      bfl[i] = *(const short8*)&Bl[rb];
    }
#pragma unroll
    for (int i = 0; i < 4; i++)
#pragma unroll
      for (int j = 0; j < 4; j++) {
        acc[i][j] = __builtin_amdgcn_mfma_f32_16x16x32_bf16(afh[i], bfh[j], acc[i][j], 0, 0, 0);
        acc[i][j] = __builtin_amdgcn_mfma_f32_16x16x32_bf16(afh[i], bfl[j], acc[i][j], 0, 0, 0);
      }
  }

  // --- epilogue: C/D layout col=lane&15, row=quad*4+reg; write bf16 (RNE) ---
#pragma unroll
  for (int i = 0; i < 4; i++) {
    const int rbase = bm + wm + i * 16 + quad * 4;
#pragma unroll
    for (int j = 0; j < 4; j++) {
      const int c = n0 + wn + j * 16 + lm;
#pragma unroll
      for (int r = 0; r < 4; r++) {
        const int row = rbase + r;
        if (row < M) C[(size_t)row * Nn + c] = f2b_rne(acc[i][j][r]);
      }
    }
  }
}

// ---------------- alpha dot products from bf16 h (ushort4 vector loads) ----------------

__global__ __launch_bounds__(256) void alpha_kernel(const unsigned short* __restrict__ h,
                                                    const float* __restrict__ a_s,
                                                    const float* __restrict__ a_d,
                                                    float* __restrict__ as_,
                                                    float* __restrict__ ad_,
                                                    int N, int F) {
  int wid = (blockIdx.x * 256 + threadIdx.x) >> 6;
  int lane = threadIdx.x & 63;
  if (wid >= N) return;
  float ss = 0.f, dd = 0.f;
  for (int c = lane * 4; c < F; c += 256) {
    ushort4v uv = *(const ushort4v*)(h + (int64_t)wid * F + c);
#pragma unroll
    for (int v = 0; v < 4; v++) {
      float x = b2f(uv[v]);
      ss += x * a_s[c + v];
      dd += x * a_d[c + v];
    }
  }
#pragma unroll
  for (int off = 32; off; off >>= 1) {
    ss += __shfl_down(ss, off);
    dd += __shfl_down(dd, off);
  }
  if (lane == 0) { as_[wid] = ss; ad_[wid] = dd; }
}

// ---------------- fused single-pass edge softmax + aggregate + bias (+relu) ----------------
// One wave per dst node. G = 64*8/F edges processed per iteration, each lane loads a
// 16B ushort8 slice of its slot's source row. Online softmax per slot (running m, ssum,
// rescaled acc); slots merged at the end via shfl_xor online-merge. Removes the whole
// separate max/sum pass over the edge list.

template <int F, bool OUTBF16>
__global__ __launch_bounds__(256) void agg_fused(const unsigned short* __restrict__ h,
                                                 const float* __restrict__ as_,
                                                 const float* __restrict__ ad_,
                                                 const int* __restrict__ rowstart,
                                                 const int* __restrict__ csr_src,
                                                 const float* __restrict__ bias,
                                                 void* __restrict__ out,
                                                 int N, int do_relu) {
  constexpr int LPR = F / 8;   // lanes per row: 16 (F=128) or 32 (F=256)
  constexpr int G = 64 / LPR;  // edges in flight per wave-iteration: 4 or 2
  int wid = (blockIdx.x * 256 + threadIdx.x) >> 6;
  int lane = threadIdx.x & 63;
  if (wid >= N) return;
  int r0 = rowstart[wid], r1 = rowstart[wid + 1];
  float adn = ad_[wid];
  const int slot = lane / LPR;
  const int cpos = (lane % LPR) * 8;

  float m = -1e30f, ssum = 0.f;
  float acc[8];
#pragma unroll
  for (int v = 0; v < 8; v++) acc[v] = 0.f;

  // software-pipelined csr index load (next iteration's src in flight)
  int idx0 = r0 + slot;
  bool ok = idx0 < r1;
  int s = csr_src[ok ? idx0 : r0];

  for (int k = r0; k < r1; k += G) {
    const int s_cur = s;
    const bool ok_cur = ok;
    int idxn = k + G + slot;
    ok = idxn < r1;
    s = csr_src[ok ? idxn : r0];

    float av = as_[s_cur];                                              // L2-resident
    ushort8 row = *(const ushort8*)(h + (size_t)s_cur * F + cpos);      // 16B/lane, 1KB/wave

    float e = ok_cur ? leaky(av + adn) : -1e30f;
    float mn = fmaxf(m, e);
    float sc = __expf(m - mn);                 // 1.0 unless new max
    float wgt = ok_cur ? __expf(e - mn) : 0.f; // padded slots contribute nothing
    ssum = ssum * sc + wgt;
    m = mn;
#pragma unroll
    for (int v = 0; v < 8; v++) acc[v] = acc[v] * sc + wgt * b2f(row[v]);
  }

  // merge slots: online-softmax merge across lane groups (off = LPR, 2*LPR, ...)
#pragma unroll
  for (int off = LPR; off < 64; off <<= 1) {
    float mo = __shfl_xor(m, off);
    float so = __shfl_xor(ssum, off);
    float ao[8];
#pragma unroll
    for (int v = 0; v < 8; v++) ao[v] = __shfl_xor(acc[v], off);
    float mn = fmaxf(m, mo);
    float sa = __expf(m - mn), sb = __expf(mo - mn);
    ssum = ssum * sa + so * sb;
#pragma unroll
    for (int v = 0; v < 8; v++) acc[v] = acc[v] * sa + ao[v] * sb;
    m = mn;
  }

  if (lane < LPR) {
    float inv = 1.f / ssum;   // self-loop guarantees ssum > 0
    float o[8];
#pragma unroll
    for (int v = 0; v < 8; v++) {
      float x = acc[v] * inv + bias[cpos + v];
      if (do_relu) x = fmaxf(x, 0.f);
      o[v] = x;
    }
    if (OUTBF16) {
      unsigned short u[8];
#pragma unroll
      for (int v = 0; v < 8; v++) u[v] = f2b_rne(o[v]);
      *(ushort8*)((unsigned short*)out + (size_t)wid * F + cpos) = *(ushort8*)u;
    } else {
      float* op = (float*)out + (size_t)wid * F + cpos;
      *(f32x4*)op = *(f32x4*)&o[0];
      *(f32x4*)(op + 4) = *(f32x4*)&o[4];
    }
  }
}

// ---------------- layer 3: GEMM (K x 2) + alpha3, wave per row (f32x4 loads) ----------------

__global__ __launch_bounds__(256) void gemm3_kernel(const float* __restrict__ h,
                                                    const float* __restrict__ W3,
                                                    const float* __restrict__ a3s,
                                                    const float* __restrict__ a3d,
                                                    float* __restrict__ h3,
                                                    float* __restrict__ as_,
                                                    float* __restrict__ ad_,
                                                    int N, int K) {
  int wid = (blockIdx.x * 256 + threadIdx.x) >> 6;
  int lane = threadIdx.x & 63;
  if (wid >= N) return;
  float c0 = 0.f, c1 = 0.f;
  const float* hp = h + (int64_t)wid * K;
  for (int k = lane * 4; k < K; k += 256) {
    f32x4 v = *(const f32x4*)(hp + k);
#pragma unroll
    for (int j = 0; j < 4; j++) {
      c0 += v[j] * W3[(k + j) * 2 + 0];
      c1 += v[j] * W3[(k + j) * 2 + 1];
    }
  }
#pragma unroll
  for (int off = 32; off; off >>= 1) {
    c0 += __shfl_down(c0, off);
    c1 += __shfl_down(c1, off);
  }
  if (lane == 0) {
    h3[wid * 2 + 0] = c0;
    h3[wid * 2 + 1] = c1;
    as_[wid] = c0 * a3s[0] + c1 * a3s[1];
    ad_[wid] = c0 * a3d[0] + c1 * a3d[1];
  }
}

// ---------------- layer 3: single-pass online aggregate + bias + 2-class softmax ----------------

__global__ __launch_bounds__(256) void agg3_kernel(const float* __restrict__ h3,
                                                   const float* __restrict__ as_,
                                                   const float* __restrict__ ad_,
                                                   const int* __restrict__ rowstart,
                                                   const int* __restrict__ csr_src,
                                                   const float* __restrict__ b3,
                                                   float* __restrict__ out, int N) {
  int wid = (blockIdx.x * 256 + threadIdx.x) >> 6;
  int lane = threadIdx.x & 63;
  if (wid >= N) return;
  int r0 = rowstart[wid], r1 = rowstart[wid + 1];
  float adn = ad_[wid];

  float m = -1e30f, ssum = 0.f, a0 = 0.f, a1 = 0.f;
  for (int i = r0 + lane; i < r1; i += 64) {
    int s = csr_src[i];
    float e = leaky(as_[s] + adn);
    f32x2 hv = *(const f32x2*)(h3 + 2 * (int64_t)s);
    float mn = fmaxf(m, e);
    float sc = __expf(m - mn), w = __expf(e - mn);
    ssum = ssum * sc + w;
    a0 = a0 * sc + w * hv[0];
    a1 = a1 * sc + w * hv[1];
    m = mn;
  }
#pragma unroll
  for (int off = 32; off; off >>= 1) {
    float mo = __shfl_xor(m, off);
    float so = __shfl_xor(ssum, off);
    float b0 = __shfl_xor(a0, off);
    float b1 = __shfl_xor(a1, off);
    float mn = fmaxf(m, mo);
    float sa = __expf(m - mn), sb = __expf(mo - mn);
    ssum = ssum * sa + so * sb;
    a0 = a0 * sa + b0 * sb;
    a1 = a1 * sa + b1 * sb;
    m = mn;
  }
  if (lane == 0) {
    float inv = 1.f / ssum;
    float o0 = a0 * inv + b3[0];
    float o1 = a1 * inv + b3[1];
    float mm = fmaxf(o0, o1);
    float e0 = __expf(o0 - mm), e1 = __expf(o1 - mm);
    float d = e0 + e1;
    out[wid * 2 + 0] = e0 / d;
    out[wid * 2 + 1] = e1 / d;
  }
}

// ---------------- launcher ----------------

extern "C" void kernel_launch(void* const* d_in, const int* in_sizes, int n_in,
                              void* d_out, int out_size, void* d_ws, size_t ws_size,
                              hipStream_t stream) {
  const float* x   = (const float*)d_in[0];
  const int*   ei  = (const int*)d_in[1];
  const float* W1  = (const float*)d_in[3];
  const float* a1s = (const float*)d_in[4];
  const float* a1d = (const float*)d_in[5];
  const float* b1  = (const float*)d_in[6];
  const float* W2  = (const float*)d_in[7];
  const float* a2s = (const float*)d_in[8];
  const float* a2d = (const float*)d_in[9];
  const float* b2  = (const float*)d_in[10];
  const float* W3  = (const float*)d_in[11];
  const float* a3s = (const float*)d_in[12];
  const float* a3d = (const float*)d_in[13];
  const float* b3  = (const float*)d_in[14];

  int N   = in_sizes[2];
  int E   = in_sizes[1] / 2;
  int FIN = in_sizes[0] / N;    // 784
  int d1  = in_sizes[4];        // 128
  int d2  = in_sizes[8];        // 256
  int Kp1 = ((FIN + 31) / 32) * 32;  // 800

  // workspace carve
  char* p = (char*)d_ws;
  unsigned short* hbuf = (unsigned short*)p; p += (size_t)N * d2 * sizeof(float);
  float* buf2 = (float*)p; p += (size_t)N * d2 * sizeof(float);
  float* h3   = (float*)p; p += (size_t)N * 2 * sizeof(float);
  float* as_  = (float*)p; p += (size_t)N * sizeof(float);
  float* ad_  = (float*)p; p += (size_t)N * sizeof(float);
  int* deg      = (int*)p; p += (size_t)N * sizeof(int);
  int* rowstart = (int*)p; p += (size_t)(N + 1) * sizeof(int);
  int* cursor   = (int*)p; p += (size_t)N * sizeof(int);
  int* bsum     = (int*)p; p += 1024 * sizeof(int);
  int* csr      = (int*)p; p += (size_t)(E + N) * sizeof(int);
  p = (char*)(((uintptr_t)p + 255) & ~(uintptr_t)255);
  short* w1h = (short*)p; p += (size_t)d1 * Kp1 * sizeof(short);
  short* w1l = (short*)p; p += (size_t)d1 * Kp1 * sizeof(short);
  short* w2h = (short*)p; p += (size_t)d2 * d1 * sizeof(short);
  short* w2l = (short*)p; p += (size_t)d2 * d1 * sizeof(short);
  p = (char*)(((uintptr_t)p + 255) & ~(uintptr_t)255);
  short* h1b = (short*)p; p += (size_t)N * d1 * sizeof(short);  // bf16 layer-1 agg output

  // CSR build (multi-block scan; nb<=256 requires N<=262144)
  hipMemsetAsync(deg, 0, (size_t)N * sizeof(int), stream);
  int tot = E + N;
  hist_kernel<<<(tot + 255) / 256, 256, 0, stream>>>(ei, deg, E, N);
  int nb = (N + 1023) / 1024;
  scan_phaseA<<<nb, 256, 0, stream>>>(deg, bsum, N);
  scan_phaseB<<<1, 256, 0, stream>>>(bsum, rowstart, nb, N);
  scan_phaseC<<<nb, 256, 0, stream>>>(deg, bsum, rowstart, cursor, N);
  scatter_kernel<<<(tot + 255) / 256, 256, 0, stream>>>(ei, cursor, csr, E, N);

  // weight transpose+split (tiny)
  convw_kernel<<<(d1 * Kp1 + 255) / 256, 256, 0, stream>>>(W1, w1h, w1l, FIN, d1, Kp1);
  convw_kernel<<<(d2 * d1 + 255) / 256, 256, 0, stream>>>(W2, w2h, w2l, d1, d2, d1);

  int wb = (N + 3) / 4;  // wave-per-node, 4 waves/block

  // layer 1: x@W1 -> hbuf bf16 [N,128]; fused agg -> h1b bf16 (relu)
  {
    dim3 g((N + 127) / 128, d1 / 128);
    mfma_gemm_split<false><<<g, 256, 0, stream>>>(x, nullptr, w1h, w1l, hbuf, N, d1, FIN, Kp1);
    alpha_kernel<<<wb, 256, 0, stream>>>(hbuf, a1s, a1d, as_, ad_, N, d1);
    agg_fused<128, true><<<wb, 256, 0, stream>>>(hbuf, as_, ad_, rowstart, csr, b1, h1b, N, 1);
  }
  // layer 2: h1b(bf16)@W2 -> hbuf bf16 [N,256]; fused agg -> buf2 fp32 (relu)
  {
    dim3 g((N + 127) / 128, d2 / 128);
    mfma_gemm_split<true><<<g, 256, 0, stream>>>(nullptr, h1b, w2h, w2l, hbuf, N, d2, d1, d1);
    alpha_kernel<<<wb, 256, 0, stream>>>(hbuf, a2s, a2d, as_, ad_, N, d2);
    agg_fused<256, false><<<wb, 256, 0, stream>>>(hbuf, as_, ad_, rowstart, csr, b2, buf2, N, 1);
  }
  // layer 3: buf2@W3 -> h3 [N,2]; single-pass agg + bias + softmax -> d_out
  {
    gemm3_kernel<<<wb, 256, 0, stream>>>(buf2, W3, a3s, a3d, h3, as_, ad_, N, d2);
    agg3_kernel<<<wb, 256, 0, stream>>>(h3, as_, ad_, rowstart, csr, b3, (float*)d_out, N);
  }
}

// Round 2
// 997.346 us; speedup vs baseline: 1.0551x; 1.0077x over previous
//
#include <hip/hip_runtime.h>
#include <cstdint>

#define NEG_SLOPE 0.2f

typedef __attribute__((ext_vector_type(8))) short short8;     // 8 bf16 = 4 VGPRs
typedef __attribute__((ext_vector_type(8))) unsigned short ushort8;
typedef __attribute__((ext_vector_type(4))) float f32x4;
typedef __attribute__((ext_vector_type(2))) float f32x2;
typedef __attribute__((ext_vector_type(4))) unsigned short ushort4v;

// split fp32 v into bf16 hi + bf16 lo (truncation; hi+lo ~ v to ~2^-16 rel)
__device__ inline void split_bf16(float v, short& hi, short& lo) {
  unsigned u = __builtin_bit_cast(unsigned, v);
  hi = (short)(u >> 16);
  float hif = __builtin_bit_cast(float, u & 0xffff0000u);
  float r = v - hif;
  lo = (short)(__builtin_bit_cast(unsigned, r) >> 16);
}

__device__ inline float b2f(unsigned short u) {
  return __builtin_bit_cast(float, (unsigned)u << 16);
}
__device__ inline unsigned short f2b_rne(float f) {
  unsigned u = __builtin_bit_cast(unsigned, f);
  return (unsigned short)((u + 0x7fffu + ((u >> 16) & 1u)) >> 16);
}
__device__ inline float leaky(float e) { return e > 0.f ? e : NEG_SLOPE * e; }

// XOR swizzle of the 16B unit (8 bf16) within a 32-element block, keyed by row.
// Writer (convw/agg1 global layout) and reader (GEMM ds_read) share this involution.
// Bank math: ds_read_b128, 16 lanes (consecutive rows, fixed quad) -> slots
// (4*(row&1) + quad^((row>>1)&3)) mod 8 covers all 8 bank-slots 2-way = conflict-free.
__device__ inline int swz_unit(int u, int row) { return u ^ ((row >> 1) & 3); }

// async global->LDS, 16B per lane; LDS dest is wave-uniform base + lane*16
__device__ inline void g2l16(const short* g, short* l) {
  __builtin_amdgcn_global_load_lds(
      (const __attribute__((address_space(1))) unsigned int*)(const void*)g,
      (__attribute__((address_space(3))) unsigned int*)(void*)l, 16, 0, 0);
}

// ---------------- CSR build ----------------

__global__ __launch_bounds__(256) void hist_kernel(const int* __restrict__ ei,
                                                   int* __restrict__ deg, int E, int N) {
  int e = blockIdx.x * 256 + threadIdx.x;
  int total = E + N;
  if (e >= total) return;
  int d = (e < E) ? ei[E + e] : (e - E);   // self-loop for virtual edges
  atomicAdd(&deg[d], 1);
}

// ---- 3-phase device-wide exclusive scan of deg[0..n) (chunk=1024/block; n<=262144) ----

__global__ __launch_bounds__(256) void scan_phaseA(const int* __restrict__ deg,
                                                   int* __restrict__ bsum, int n) {
  __shared__ int red[256];
  int base = blockIdx.x * 1024;
  int s = 0;
#pragma unroll
  for (int j = 0; j < 4; j++) {
    int i = base + threadIdx.x + j * 256;
    if (i < n) s += deg[i];
  }
  red[threadIdx.x] = s;
  __syncthreads();
  for (int off = 128; off; off >>= 1) {
    if (threadIdx.x < off) red[threadIdx.x] += red[threadIdx.x + off];
    __syncthreads();
  }
  if (threadIdx.x == 0) bsum[blockIdx.x] = red[0];
}

__global__ __launch_bounds__(256) void scan_phaseB(int* __restrict__ bsum,
                                                   int* __restrict__ rowstart,
                                                   int nb, int n) {
  __shared__ int sc[256];
  int tid = threadIdx.x;
  int v = (tid < nb) ? bsum[tid] : 0;
  sc[tid] = v;
  __syncthreads();
  for (int off = 1; off < 256; off <<= 1) {
    int t = (tid >= off) ? sc[tid - off] : 0;
    __syncthreads();
    sc[tid] += t;
    __syncthreads();
  }
  if (tid < nb) bsum[tid] = sc[tid] - v;   // exclusive block offsets
  if (tid == 0) rowstart[n] = sc[255];     // grand total
}

__global__ __launch_bounds__(256) void scan_phaseC(const int* __restrict__ deg,
                                                   const int* __restrict__ bsum,
                                                   int* __restrict__ rowstart,
                                                   int* __restrict__ cursor, int n) {
  __shared__ int tsum[256];
  int tid = threadIdx.x;
  int base = blockIdx.x * 1024 + tid * 4;  // 4 contiguous per thread
  int d[4];
  int s = 0;
#pragma unroll
  for (int j = 0; j < 4; j++) {
    int i = base + j;
    d[j] = (i < n) ? deg[i] : 0;
    s += d[j];
  }
  tsum[tid] = s;
  __syncthreads();
  for (int off = 1; off < 256; off <<= 1) {
    int t = (tid >= off) ? tsum[tid - off] : 0;
    __syncthreads();
    tsum[tid] += t;
    __syncthreads();
  }
  int run = bsum[blockIdx.x] + tsum[tid] - s;  // exclusive prefix for this thread
#pragma unroll
  for (int j = 0; j < 4; j++) {
    int i = base + j;
    if (i < n) { rowstart[i] = run; cursor[i] = run; }
    run += d[j];
  }
}

__global__ __launch_bounds__(256) void scatter_kernel(const int* __restrict__ ei,
                                                      int* __restrict__ cursor,
                                                      int* __restrict__ csr_src, int E, int N) {
  int e = blockIdx.x * 256 + threadIdx.x;
  int total = E + N;
  if (e >= total) return;
  int s, d;
  if (e < E) { s = ei[e]; d = ei[E + e]; }
  else       { s = e - E; d = e - E; }
  int p = atomicAdd(&cursor[d], 1);
  csr_src[p] = s;
}

// ---------------- weight convert: W[K][N] fp32 -> Wt_hi/Wt_lo [N][Kp] bf16 ----------------
// zero-pad + intra-32-block unit swizzle (for conflict-free ds_read after global_load_lds)

__global__ __launch_bounds__(256) void convw_kernel(const float* __restrict__ W,
                                                    short* __restrict__ Whi,
                                                    short* __restrict__ Wlo,
                                                    int K, int N, int Kp) {
  int idx = blockIdx.x * 256 + threadIdx.x;
  if (idx >= N * Kp) return;
  int n = idx / Kp, k = idx % Kp;
  float v = (k < K) ? W[(size_t)k * N + n] : 0.f;
  short hi, lo;
  split_bf16(v, hi, lo);
  int ks = (k & ~31) | (swz_unit((k >> 3) & 3, n) << 3) | (k & 7);
  Whi[(size_t)n * Kp + ks] = hi;
  Wlo[(size_t)n * Kp + ks] = lo;
}

// ---------------- 2-stream MFMA GEMM: C = round_bf16(A) @ (Bhi+Blo)^T ----------------
// B (and A in the ABF16 path) staged via global_load_lds from pre-swizzled global layout;
// fp32 A (layer 1) reg-staged with RNE conversion into padded-LDK LDS.
// Epilogue: fused alpha_src/alpha_dst dot products (atomicAdd into zeroed as_/ad_).

#define LDK 40   // padded LDS k-stride for the fp32-A path (80B rows -> 2-way aliasing, free)

template <bool ABF16>
__global__ __launch_bounds__(256, 3) void mfma_gemm_split(
    const float* __restrict__ Af, const short* __restrict__ Ab,
    const short* __restrict__ Bhi, const short* __restrict__ Blo,
    unsigned short* __restrict__ C,
    const float* __restrict__ a_s, const float* __restrict__ a_d,
    float* __restrict__ as_g, float* __restrict__ ad_g,
    int M, int Nn, int K, int Kp) {
  __shared__ short Ah[128 * LDK];          // fp32 path: [128][LDK]; bf16 path: [128][32] linear
  __shared__ short Bh2[128 * 32], Bl2[128 * 32];

  const int t = threadIdx.x;
  const int bm = blockIdx.x * 128;
  const int n0 = blockIdx.y * 128;

  const int srow = t >> 1;        // staging row 0..127 (fp32-A path)
  const int shalf = t & 1;
  const bool arow_ok = (bm + srow) < M;

  const int w = t >> 6, lane = t & 63;
  const int wm = (w >> 1) * 64, wn = (w & 1) * 64;  // wave's 64x64 quadrant
  const int lm = lane & 15, quad = lane >> 4;

  f32x4 acc[4][4];
#pragma unroll
  for (int i = 0; i < 4; i++)
#pragma unroll
    for (int j = 0; j < 4; j++) acc[i][j] = (f32x4)(0.f);

  for (int k0 = 0; k0 < Kp; k0 += 32) {
    __syncthreads();

    // --- B via global_load_lds (2x 1KB per wave per buffer; source pre-swizzled) ---
#pragma unroll
    for (int i = 0; i < 2; i++) {
      const int rb = (w << 5) + (i << 4);                 // LDS row base of this 1KB chunk
      const size_t go = (size_t)(n0 + rb + (lane >> 2)) * Kp + k0 + (lane & 3) * 8;
      g2l16(Bhi + go, &Bh2[rb * 32]);
      g2l16(Blo + go, &Bl2[rb * 32]);
    }

    // --- A ---
    if constexpr (ABF16) {
#pragma unroll
      for (int i = 0; i < 2; i++) {
        const int rb = (w << 5) + (i << 4);
        const size_t go = (size_t)(bm + rb + (lane >> 2)) * Kp + k0 + (lane & 3) * 8;
        g2l16(Ab + go, &Ah[rb * 32]);       // rows >= M read padded slack; rows discarded later
      }
    } else {
      const int kbase = k0 + shalf * 16;
      f32x4 v0 = (f32x4)(0.f), v1 = (f32x4)(0.f), v2 = (f32x4)(0.f), v3 = (f32x4)(0.f);
      if (arow_ok && kbase < K) {   // K % 16 == 0 -> chunk fully in or out
        const f32x4* p = (const f32x4*)(Af + (size_t)(bm + srow) * K + kbase);
        v0 = p[0]; v1 = p[1]; v2 = p[2]; v3 = p[3];
      }
      float f[16] = {v0[0], v0[1], v0[2], v0[3], v1[0], v1[1], v1[2], v1[3],
                     v2[0], v2[1], v2[2], v2[3], v3[0], v3[1], v3[2], v3[3]};
      unsigned short hi[16];
#pragma unroll
      for (int j = 0; j < 16; j++) hi[j] = f2b_rne(f[j]);
      const int la = srow * LDK + shalf * 16;
      *(short8*)&Ah[la] = *(short8*)&hi[0];
      *(short8*)&Ah[la + 8] = *(short8*)&hi[8];
    }
    __syncthreads();   // compiler drains vmcnt (gload_lds) + lgkm here

    // --- fragments + 32 MFMAs ---
    short8 afh[4], bfh[4], bfl[4];
#pragma unroll
    for (int i = 0; i < 4; i++) {
      const int ar = wm + i * 16 + lm;
      if constexpr (ABF16)
        afh[i] = *(const short8*)&Ah[ar * 32 + swz_unit(quad, ar) * 8];
      else
        afh[i] = *(const short8*)&Ah[ar * LDK + quad * 8];
      const int br = wn + i * 16 + lm;
      const int bo = br * 32 + swz_unit(quad, br) * 8;
      bfh[i] = *(const short8*)&Bh2[bo];
      bfl[i] = *(const short8*)&Bl2[bo];
    }
#pragma unroll
    for (int i = 0; i < 4; i++)
#pragma unroll
      for (int j = 0; j < 4; j++) {
        acc[i][j] = __builtin_amdgcn_mfma_f32_16x16x32_bf16(afh[i], bfh[j], acc[i][j], 0, 0, 0);
        acc[i][j] = __builtin_amdgcn_mfma_f32_16x16x32_bf16(afh[i], bfl[j], acc[i][j], 0, 0, 0);
      }
  }

  // --- epilogue 1: fused alpha dot products from fp32 acc ---
  {
    float asv[4], adv[4];
#pragma unroll
    for (int j = 0; j < 4; j++) {
      const int c = n0 + wn + j * 16 + lm;
      asv[j] = a_s[c];
      adv[j] = a_d[c];
    }
#pragma unroll
    for (int i = 0; i < 4; i++)
#pragma unroll
      for (int r = 0; r < 4; r++) {
        float ss = 0.f, dd = 0.f;
#pragma unroll
        for (int j = 0; j < 4; j++) {
          ss += acc[i][j][r] * asv[j];
          dd += acc[i][j][r] * adv[j];
        }
#pragma unroll
        for (int off = 1; off < 16; off <<= 1) {
          ss += __shfl_xor(ss, off);
          dd += __shfl_xor(dd, off);
        }
        if (lm == 0) {
          const int row = bm + wm + i * 16 + quad * 4 + r;
          if (row < M) {
            atomicAdd(&as_g[row], ss);
            atomicAdd(&ad_g[row], dd);
          }
        }
      }
  }

  // --- epilogue 2: C write, bf16 RNE; C/D layout col=lane&15, row=quad*4+reg ---
#pragma unroll
  for (int i = 0; i < 4; i++) {
    const int rbase = bm + wm + i * 16 + quad * 4;
#pragma unroll
    for (int j = 0; j < 4; j++) {
      const int c = n0 + wn + j * 16 + lm;
#pragma unroll
      for (int r = 0; r < 4; r++) {
        const int row = rbase + r;
        if (row < M) C[(size_t)row * Nn + c] = f2b_rne(acc[i][j][r]);
      }
    }
  }
}

// ---------------- fused single-pass edge softmax + aggregate + bias (+relu) ----------------
// One wave per dst node; G = 64*8/F edges in flight; exact defer-max (rescale only when a
// new max appears in some lane). SWZ: write output pre-swizzled for GEMM global_load_lds.

template <int F, bool OUTBF16, bool SWZ>
__global__ __launch_bounds__(256) void agg_fused(const unsigned short* __restrict__ h,
                                                 const float* __restrict__ as_,
                                                 const float* __restrict__ ad_,
                                                 const int* __restrict__ rowstart,
                                                 const int* __restrict__ csr_src,
                                                 const float* __restrict__ bias,
                                                 void* __restrict__ out,
                                                 int N, int do_relu) {
  constexpr int LPR = F / 8;   // lanes per row: 16 (F=128) or 32 (F=256)
  constexpr int G = 64 / LPR;  // edges in flight per wave-iteration: 4 or 2
  int wid = (blockIdx.x * 256 + threadIdx.x) >> 6;
  int lane = threadIdx.x & 63;
  if (wid >= N) return;
  int r0 = rowstart[wid], r1 = rowstart[wid + 1];
  float adn = ad_[wid];
  const int slot = lane / LPR;
  const int cpos = (lane % LPR) * 8;

  float m = -1e30f, ssum = 0.f;
  float acc[8];
#pragma unroll
  for (int v = 0; v < 8; v++) acc[v] = 0.f;

  // software-pipelined csr index load (next iteration's src in flight)
  int idx0 = r0 + slot;
  bool ok = idx0 < r1;
  int s = csr_src[ok ? idx0 : r0];

  for (int k = r0; k < r1; k += G) {
    const int s_cur = s;
    const bool ok_cur = ok;
    int idxn = k + G + slot;
    ok = idxn < r1;
    s = csr_src[ok ? idxn : r0];

    float av = as_[s_cur];                                              // L2-resident
    ushort8 row = *(const ushort8*)(h + (size_t)s_cur * F + cpos);      // 16B/lane, 1KB/wave

    float e = ok_cur ? leaky(av + adn) : -1e30f;
    if (!__all(e <= m)) {           // exact defer: rescale only on a new max somewhere
      float mn = fmaxf(m, e);
      float sc = __expf(m - mn);    // 1.0 for lanes whose max didn't move
      ssum *= sc;
#pragma unroll
      for (int v = 0; v < 8; v++) acc[v] *= sc;
      m = mn;
    }
    float wgt = ok_cur ? __expf(e - m) : 0.f;
    ssum += wgt;
#pragma unroll
    for (int v = 0; v < 8; v++) acc[v] += wgt * b2f(row[v]);
  }

  // merge slots: online-softmax merge across lane groups (off = LPR, 2*LPR, ...)
#pragma unroll
  for (int off = LPR; off < 64; off <<= 1) {
    float mo = __shfl_xor(m, off);
    float so = __shfl_xor(ssum, off);
    float ao[8];
#pragma unroll
    for (int v = 0; v < 8; v++) ao[v] = __shfl_xor(acc[v], off);
    float mn = fmaxf(m, mo);
    float sa = __expf(m - mn), sb = __expf(mo - mn);
    ssum = ssum * sa + so * sb;
#pragma unroll
    for (int v = 0; v < 8; v++) acc[v] = acc[v] * sa + ao[v] * sb;
    m = mn;
  }

  if (lane < LPR) {
    float inv = 1.f / ssum;   // self-loop guarantees ssum > 0
    float o[8];
#pragma unroll
    for (int v = 0; v < 8; v++) {
      float x = acc[v] * inv + bias[cpos + v];
      if (do_relu) x = fmaxf(x, 0.f);
      o[v] = x;
    }
    if (OUTBF16) {
      unsigned short u[8];
#pragma unroll
      for (int v = 0; v < 8; v++) u[v] = f2b_rne(o[v]);
      int cdst = SWZ ? (((lane >> 2) << 5) + (swz_unit(lane & 3, wid) << 3)) : cpos;
      *(ushort8*)((unsigned short*)out + (size_t)wid * F + cdst) = *(ushort8*)u;
    } else {
      float* op = (float*)out + (size_t)wid * F + cpos;
      *(f32x4*)op = *(f32x4*)&o[0];
      *(f32x4*)(op + 4) = *(f32x4*)&o[4];
    }
  }
}

// ---------------- layer 3: GEMM (K x 2) + alpha3, wave per row (f32x4 loads) ----------------

__global__ __launch_bounds__(256) void gemm3_kernel(const float* __restrict__ h,
                                                    const float* __restrict__ W3,
                                                    const float* __restrict__ a3s,
                                                    const float* __restrict__ a3d,
                                                    float* __restrict__ h3,
                                                    float* __restrict__ as_,
                                                    float* __restrict__ ad_,
                                                    int N, int K) {
  int wid = (blockIdx.x * 256 + threadIdx.x) >> 6;
  int lane = threadIdx.x & 63;
  if (wid >= N) return;
  float c0 = 0.f, c1 = 0.f;
  const float* hp = h + (int64_t)wid * K;
  for (int k = lane * 4; k < K; k += 256) {
    f32x4 v = *(const f32x4*)(hp + k);
#pragma unroll
    for (int j = 0; j < 4; j++) {
      c0 += v[j] * W3[(k + j) * 2 + 0];
      c1 += v[j] * W3[(k + j) * 2 + 1];
    }
  }
#pragma unroll
  for (int off = 32; off; off >>= 1) {
    c0 += __shfl_down(c0, off);
    c1 += __shfl_down(c1, off);
  }
  if (lane == 0) {
    h3[wid * 2 + 0] = c0;
    h3[wid * 2 + 1] = c1;
    as_[wid] = c0 * a3s[0] + c1 * a3s[1];
    ad_[wid] = c0 * a3d[0] + c1 * a3d[1];
  }
}

// ---------------- layer 3: single-pass online aggregate + bias + 2-class softmax ----------------

__global__ __launch_bounds__(256) void agg3_kernel(const float* __restrict__ h3,
                                                   const float* __restrict__ as_,
                                                   const float* __restrict__ ad_,
                                                   const int* __restrict__ rowstart,
                                                   const int* __restrict__ csr_src,
                                                   const float* __restrict__ b3,
                                                   float* __restrict__ out, int N) {
  int wid = (blockIdx.x * 256 + threadIdx.x) >> 6;
  int lane = threadIdx.x & 63;
  if (wid >= N) return;
  int r0 = rowstart[wid], r1 = rowstart[wid + 1];
  float adn = ad_[wid];

  float m = -1e30f, ssum = 0.f, a0 = 0.f, a1 = 0.f;
  for (int i = r0 + lane; i < r1; i += 64) {
    int s = csr_src[i];
    float e = leaky(as_[s] + adn);
    f32x2 hv = *(const f32x2*)(h3 + 2 * (int64_t)s);
    if (!__all(e <= m)) {
      float mn = fmaxf(m, e);
      float sc = __expf(m - mn);
      ssum *= sc; a0 *= sc; a1 *= sc;
      m = mn;
    }
    float w = __expf(e - m);
    ssum += w;
    a0 += w * hv[0];
    a1 += w * hv[1];
  }
#pragma unroll
  for (int off = 32; off; off >>= 1) {
    float mo = __shfl_xor(m, off);
    float so = __shfl_xor(ssum, off);
    float b0 = __shfl_xor(a0, off);
    float b1 = __shfl_xor(a1, off);
    float mn = fmaxf(m, mo);
    float sa = __expf(m - mn), sb = __expf(mo - mn);
    ssum = ssum * sa + so * sb;
    a0 = a0 * sa + b0 * sb;
    a1 = a1 * sa + b1 * sb;
    m = mn;
  }
  if (lane == 0) {
    float inv = 1.f / ssum;
    float o0 = a0 * inv + b3[0];
    float o1 = a1 * inv + b3[1];
    float mm = fmaxf(o0, o1);
    float e0 = __expf(o0 - mm), e1 = __expf(o1 - mm);
    float d = e0 + e1;
    out[wid * 2 + 0] = e0 / d;
    out[wid * 2 + 1] = e1 / d;
  }
}

// ---------------- launcher ----------------

extern "C" void kernel_launch(void* const* d_in, const int* in_sizes, int n_in,
                              void* d_out, int out_size, void* d_ws, size_t ws_size,
                              hipStream_t stream) {
  const float* x   = (const float*)d_in[0];
  const int*   ei  = (const int*)d_in[1];
  const float* W1  = (const float*)d_in[3];
  const float* a1s = (const float*)d_in[4];
  const float* a1d = (const float*)d_in[5];
  const float* b1  = (const float*)d_in[6];
  const float* W2  = (const float*)d_in[7];
  const float* a2s = (const float*)d_in[8];
  const float* a2d = (const float*)d_in[9];
  const float* b2  = (const float*)d_in[10];
  const float* W3  = (const float*)d_in[11];
  const float* a3s = (const float*)d_in[12];
  const float* a3d = (const float*)d_in[13];
  const float* b3  = (const float*)d_in[14];

  int N   = in_sizes[2];
  int E   = in_sizes[1] / 2;
  int FIN = in_sizes[0] / N;    // 784
  int d1  = in_sizes[4];        // 128
  int d2  = in_sizes[8];        // 256
  int Kp1 = ((FIN + 31) / 32) * 32;  // 800

  // workspace carve
  char* p = (char*)d_ws;
  unsigned short* hbuf = (unsigned short*)p; p += (size_t)N * d2 * sizeof(float);
  float* buf2 = (float*)p; p += (size_t)N * d2 * sizeof(float);
  float* h3   = (float*)p; p += (size_t)N * 2 * sizeof(float);
  float* as_  = (float*)p; p += (size_t)N * sizeof(float);
  float* ad_  = (float*)p; p += (size_t)N * sizeof(float);   // contiguous after as_
  int* deg      = (int*)p; p += (size_t)N * sizeof(int);
  int* rowstart = (int*)p; p += (size_t)(N + 1) * sizeof(int);
  int* cursor   = (int*)p; p += (size_t)N * sizeof(int);
  int* bsum     = (int*)p; p += 1024 * sizeof(int);
  int* csr      = (int*)p; p += (size_t)(E + N) * sizeof(int);
  p = (char*)(((uintptr_t)p + 255) & ~(uintptr_t)255);
  short* w1h = (short*)p; p += (size_t)d1 * Kp1 * sizeof(short);
  short* w1l = (short*)p; p += (size_t)d1 * Kp1 * sizeof(short);
  short* w2h = (short*)p; p += (size_t)d2 * d1 * sizeof(short);
  short* w2l = (short*)p; p += (size_t)d2 * d1 * sizeof(short);
  p = (char*)(((uintptr_t)p + 255) & ~(uintptr_t)255);
  // +128 row slack: GEMM2's unpredicated global_load_lds reads past row N in the last tile
  short* h1b = (short*)p; p += (size_t)(N + 128) * d1 * sizeof(short);

  // CSR build (multi-block scan; nb<=256 requires N<=262144)
  hipMemsetAsync(deg, 0, (size_t)N * sizeof(int), stream);
  int tot = E + N;
  hist_kernel<<<(tot + 255) / 256, 256, 0, stream>>>(ei, deg, E, N);
  int nb = (N + 1023) / 1024;
  scan_phaseA<<<nb, 256, 0, stream>>>(deg, bsum, N);
  scan_phaseB<<<1, 256, 0, stream>>>(bsum, rowstart, nb, N);
  scan_phaseC<<<nb, 256, 0, stream>>>(deg, bsum, rowstart, cursor, N);
  scatter_kernel<<<(tot + 255) / 256, 256, 0, stream>>>(ei, cursor, csr, E, N);

  // weight transpose+split+swizzle (tiny)
  convw_kernel<<<(d1 * Kp1 + 255) / 256, 256, 0, stream>>>(W1, w1h, w1l, FIN, d1, Kp1);
  convw_kernel<<<(d2 * d1 + 255) / 256, 256, 0, stream>>>(W2, w2h, w2l, d1, d2, d1);

  int wb = (N + 3) / 4;  // wave-per-node, 4 waves/block

  // layer 1: x@W1 -> hbuf bf16 [N,128] + fused alpha; agg -> h1b bf16 swizzled (relu)
  {
    hipMemsetAsync(as_, 0, (size_t)2 * N * sizeof(float), stream);  // as_ + ad_ (contiguous)
    dim3 g((N + 127) / 128, d1 / 128);
    mfma_gemm_split<false><<<g, 256, 0, stream>>>(x, nullptr, w1h, w1l, hbuf,
                                                  a1s, a1d, as_, ad_, N, d1, FIN, Kp1);
    agg_fused<128, true, true><<<wb, 256, 0, stream>>>(hbuf, as_, ad_, rowstart, csr, b1, h1b, N, 1);
  }
  // layer 2: h1b(bf16,swz)@W2 -> hbuf bf16 [N,256] + fused alpha; agg -> buf2 fp32 (relu)
  {
    hipMemsetAsync(as_, 0, (size_t)2 * N * sizeof(float), stream);
    dim3 g((N + 127) / 128, d2 / 128);
    mfma_gemm_split<true><<<g, 256, 0, stream>>>(nullptr, h1b, w2h, w2l, hbuf,
                                                 a2s, a2d, as_, ad_, N, d2, d1, d1);
    agg_fused<256, false, false><<<wb, 256, 0, stream>>>(hbuf, as_, ad_, rowstart, csr, b2, buf2, N, 1);
  }
  // layer 3: buf2@W3 -> h3 [N,2]; single-pass agg + bias + softmax -> d_out
  {
    gemm3_kernel<<<wb, 256, 0, stream>>>(buf2, W3, a3s, a3d, h3, as_, ad_, N, d2);
    agg3_kernel<<<wb, 256, 0, stream>>>(h3, as_, ad_, rowstart, csr, b3, (float*)d_out, N);
  }
}

// Round 3
// 942.682 us; speedup vs baseline: 1.1163x; 1.0580x over previous
//
#include <hip/hip_runtime.h>
#include <cstdint>

#define NEG_SLOPE 0.2f

typedef __attribute__((ext_vector_type(8))) short short8;     // 8 bf16 = 4 VGPRs
typedef __attribute__((ext_vector_type(8))) unsigned short ushort8;
typedef __attribute__((ext_vector_type(4))) float f32x4;
typedef __attribute__((ext_vector_type(2))) float f32x2;

// split fp32 v into bf16 hi + bf16 lo (truncation; hi+lo ~ v to ~2^-16 rel)
__device__ inline void split_bf16(float v, short& hi, short& lo) {
  unsigned u = __builtin_bit_cast(unsigned, v);
  hi = (short)(u >> 16);
  float hif = __builtin_bit_cast(float, u & 0xffff0000u);
  float r = v - hif;
  lo = (short)(__builtin_bit_cast(unsigned, r) >> 16);
}

__device__ inline float b2f(unsigned short u) {
  return __builtin_bit_cast(float, (unsigned)u << 16);
}
__device__ inline unsigned short f2b_rne(float f) {
  unsigned u = __builtin_bit_cast(unsigned, f);
  return (unsigned short)((u + 0x7fffu + ((u >> 16) & 1u)) >> 16);
}
__device__ inline float leaky(float e) { return e > 0.f ? e : NEG_SLOPE * e; }

// XOR swizzle of the 16B unit (8 bf16) within a 32-element block, keyed by row.
// Writer (convw/agg1 global layout) and reader (GEMM ds_read) share this involution.
__device__ inline int swz_unit(int u, int row) { return u ^ ((row >> 1) & 3); }

// async global->LDS, 16B per lane; LDS dest is wave-uniform base + lane*16
__device__ inline void g2l16(const short* g, short* l) {
  __builtin_amdgcn_global_load_lds(
      (const __attribute__((address_space(1))) unsigned int*)(const void*)g,
      (__attribute__((address_space(3))) unsigned int*)(void*)l, 16, 0, 0);
}

// ---------------- CSR build ----------------
// hist: count degree AND record each edge's arrival rank (atomic returns old value);
// scatter then needs NO atomics.

__global__ __launch_bounds__(256) void hist_kernel(const int* __restrict__ ei,
                                                   int* __restrict__ deg,
                                                   int* __restrict__ rank, int E, int N) {
  int e = blockIdx.x * 256 + threadIdx.x;
  int total = E + N;
  if (e >= total) return;
  int d = (e < E) ? ei[E + e] : (e - E);   // self-loop for virtual edges
  rank[e] = atomicAdd(&deg[d], 1);
}

// ---- 3-phase device-wide exclusive scan of deg[0..n) (chunk=1024/block; n<=262144) ----

__global__ __launch_bounds__(256) void scan_phaseA(const int* __restrict__ deg,
                                                   int* __restrict__ bsum, int n) {
  __shared__ int red[256];
  int base = blockIdx.x * 1024;
  int s = 0;
#pragma unroll
  for (int j = 0; j < 4; j++) {
    int i = base + threadIdx.x + j * 256;
    if (i < n) s += deg[i];
  }
  red[threadIdx.x] = s;
  __syncthreads();
  for (int off = 128; off; off >>= 1) {
    if (threadIdx.x < off) red[threadIdx.x] += red[threadIdx.x + off];
    __syncthreads();
  }
  if (threadIdx.x == 0) bsum[blockIdx.x] = red[0];
}

__global__ __launch_bounds__(256) void scan_phaseB(int* __restrict__ bsum,
                                                   int* __restrict__ rowstart,
                                                   int nb, int n) {
  __shared__ int sc[256];
  int tid = threadIdx.x;
  int v = (tid < nb) ? bsum[tid] : 0;
  sc[tid] = v;
  __syncthreads();
  for (int off = 1; off < 256; off <<= 1) {
    int t = (tid >= off) ? sc[tid - off] : 0;
    __syncthreads();
    sc[tid] += t;
    __syncthreads();
  }
  if (tid < nb) bsum[tid] = sc[tid] - v;   // exclusive block offsets
  if (tid == 0) rowstart[n] = sc[255];     // grand total
}

__global__ __launch_bounds__(256) void scan_phaseC(const int* __restrict__ deg,
                                                   const int* __restrict__ bsum,
                                                   int* __restrict__ rowstart, int n) {
  __shared__ int tsum[256];
  int tid = threadIdx.x;
  int base = blockIdx.x * 1024 + tid * 4;  // 4 contiguous per thread
  int d[4];
  int s = 0;
#pragma unroll
  for (int j = 0; j < 4; j++) {
    int i = base + j;
    d[j] = (i < n) ? deg[i] : 0;
    s += d[j];
  }
  tsum[tid] = s;
  __syncthreads();
  for (int off = 1; off < 256; off <<= 1) {
    int t = (tid >= off) ? tsum[tid - off] : 0;
    __syncthreads();
    tsum[tid] += t;
    __syncthreads();
  }
  int run = bsum[blockIdx.x] + tsum[tid] - s;  // exclusive prefix for this thread
#pragma unroll
  for (int j = 0; j < 4; j++) {
    int i = base + j;
    if (i < n) rowstart[i] = run;
    run += d[j];
  }
}

__global__ __launch_bounds__(256) void scatter_kernel(const int* __restrict__ ei,
                                                      const int* __restrict__ rowstart,
                                                      const int* __restrict__ rank,
                                                      int* __restrict__ csr_src, int E, int N) {
  int e = blockIdx.x * 256 + threadIdx.x;
  int total = E + N;
  if (e >= total) return;
  int s, d;
  if (e < E) { s = ei[e]; d = ei[E + e]; }
  else       { s = e - E; d = e - E; }
  csr_src[rowstart[d] + rank[e]] = s;      // atomic-free scatter
}

// ---------------- weight convert (both layers in ONE launch) ----------------
// W[K][N] fp32 -> Wt_hi/Wt_lo [N][Kp] bf16, zero-pad + intra-32-block unit swizzle

__device__ inline void convw_one(const float* W, short* Whi, short* Wlo,
                                 int K, int N, int Kp, int idx) {
  int n = idx / Kp, k = idx % Kp;
  float v = (k < K) ? W[(size_t)k * N + n] : 0.f;
  short hi, lo;
  split_bf16(v, hi, lo);
  int ks = (k & ~31) | (swz_unit((k >> 3) & 3, n) << 3) | (k & 7);
  Whi[(size_t)n * Kp + ks] = hi;
  Wlo[(size_t)n * Kp + ks] = lo;
}

__global__ __launch_bounds__(256) void convw2_kernel(
    const float* __restrict__ Wa, short* __restrict__ ah, short* __restrict__ al,
    int Ka, int Na, int Kpa,
    const float* __restrict__ Wb, short* __restrict__ bh, short* __restrict__ bl,
    int Kb, int Nb, int Kpb) {
  int idx = blockIdx.x * 256 + threadIdx.x;
  int tot_a = Na * Kpa;
  if (idx < tot_a) convw_one(Wa, ah, al, Ka, Na, Kpa, idx);
  else if (idx - tot_a < Nb * Kpb) convw_one(Wb, bh, bl, Kb, Nb, Kpb, idx - tot_a);
}

// ---------------- 2-stream MFMA GEMM: C = round_bf16(A) @ (Bhi+Blo)^T ----------------
// Double-buffered single-barrier pipeline: issue next tile's loads BEFORE the MFMAs
// (A global->reg, B/A via global_load_lds), write A's LDS after them (issue-early /
// write-late), one __syncthreads per K-step. Epilogue fuses alpha_src/dst dots.

#define LDK 40   // padded LDS k-stride for the fp32-A path (80B rows -> 2-way aliasing, free)

template <bool ABF16>
__global__ __launch_bounds__(256, 3) void mfma_gemm_split(
    const float* __restrict__ Af, const short* __restrict__ Ab,
    const short* __restrict__ Bhi, const short* __restrict__ Blo,
    unsigned short* __restrict__ C,
    const float* __restrict__ a_s, const float* __restrict__ a_d,
    float* __restrict__ as_g, float* __restrict__ ad_g,
    int M, int Nn, int K, int Kp) {
  __shared__ short Ah[2 * 128 * LDK];                 // fp32 path [2][128][40]; bf16 path uses [2][128][32]
  __shared__ short Bh2[2 * 128 * 32], Bl2[2 * 128 * 32];

  const int t = threadIdx.x;
  const int bm = blockIdx.x * 128;
  const int n0 = blockIdx.y * 128;

  const int srow = t >> 1;        // staging row 0..127 (fp32-A path)
  const int shalf = t & 1;
  const bool arow_ok = (bm + srow) < M;

  const int w = t >> 6, lane = t & 63;
  const int wm = (w >> 1) * 64, wn = (w & 1) * 64;  // wave's 64x64 quadrant
  const int lm = lane & 15, quad = lane >> 4;
  const int nt = Kp >> 5;

  f32x4 acc[4][4];
#pragma unroll
  for (int i = 0; i < 4; i++)
#pragma unroll
    for (int j = 0; j < 4; j++) acc[i][j] = (f32x4)(0.f);

  auto stageB = [&](int buf, int k0) {
#pragma unroll
    for (int i = 0; i < 2; i++) {
      const int rb = (w << 5) + (i << 4);
      const size_t go = (size_t)(n0 + rb + (lane >> 2)) * Kp + k0 + (lane & 3) * 8;
      g2l16(Bhi + go, &Bh2[buf * 4096 + rb * 32]);
      g2l16(Blo + go, &Bl2[buf * 4096 + rb * 32]);
    }
  };
  auto stageAgl = [&](int buf, int k0) {
#pragma unroll
    for (int i = 0; i < 2; i++) {
      const int rb = (w << 5) + (i << 4);
      const size_t go = (size_t)(bm + rb + (lane >> 2)) * Kp + k0 + (lane & 3) * 8;
      g2l16(Ab + go, &Ah[buf * 4096 + rb * 32]);   // rows >= M read +128 slack; discarded later
    }
  };
  auto issueA = [&](int k0, f32x4* va) {
    const int kbase = k0 + shalf * 16;
    va[0] = va[1] = va[2] = va[3] = (f32x4)(0.f);
    if (arow_ok && kbase < K) {   // K % 16 == 0 -> chunk fully in or out
      const f32x4* p = (const f32x4*)(Af + (size_t)(bm + srow) * K + kbase);
      va[0] = p[0]; va[1] = p[1]; va[2] = p[2]; va[3] = p[3];
    }
  };
  auto writeA = [&](int buf, const f32x4* va) {
    float f[16] = {va[0][0], va[0][1], va[0][2], va[0][3], va[1][0], va[1][1], va[1][2], va[1][3],
                   va[2][0], va[2][1], va[2][2], va[2][3], va[3][0], va[3][1], va[3][2], va[3][3]};
    unsigned short hi[16];
#pragma unroll
    for (int j = 0; j < 16; j++) hi[j] = f2b_rne(f[j]);
    const int la = buf * (128 * LDK) + srow * LDK + shalf * 16;
    *(short8*)&Ah[la] = *(short8*)&hi[0];
    *(short8*)&Ah[la + 8] = *(short8*)&hi[8];
  };
  auto compute = [&](int buf) {
    short8 afh[4], bfh[4], bfl[4];
#pragma unroll
    for (int i = 0; i < 4; i++) {
      const int ar = wm + i * 16 + lm;
      if constexpr (ABF16)
        afh[i] = *(const short8*)&Ah[buf * 4096 + ar * 32 + swz_unit(quad, ar) * 8];
      else
        afh[i] = *(const short8*)&Ah[buf * (128 * LDK) + ar * LDK + quad * 8];
      const int br = wn + i * 16 + lm;
      const int bo = buf * 4096 + br * 32 + swz_unit(quad, br) * 8;
      bfh[i] = *(const short8*)&Bh2[bo];
      bfl[i] = *(const short8*)&Bl2[bo];
    }
#pragma unroll
    for (int i = 0; i < 4; i++)
#pragma unroll
      for (int j = 0; j < 4; j++) {
        acc[i][j] = __builtin_amdgcn_mfma_f32_16x16x32_bf16(afh[i], bfh[j], acc[i][j], 0, 0, 0);
        acc[i][j] = __builtin_amdgcn_mfma_f32_16x16x32_bf16(afh[i], bfl[j], acc[i][j], 0, 0, 0);
      }
  };

  // prologue: stage tile 0 into buf 0
  if constexpr (ABF16) {
    stageAgl(0, 0);
    stageB(0, 0);
  } else {
    f32x4 va[4];
    issueA(0, va);
    stageB(0, 0);
    writeA(0, va);
  }
  __syncthreads();

  for (int t_ = 0; t_ < nt; ++t_) {
    const int cur = t_ & 1;
    const bool more = t_ + 1 < nt;
    f32x4 va[4];
    if (more) {                      // issue next tile's loads BEFORE the MFMAs
      const int kn = (t_ + 1) << 5;
      if constexpr (ABF16) stageAgl(cur ^ 1, kn);
      else issueA(kn, va);
      stageB(cur ^ 1, kn);
    }
    compute(cur);                    // MFMA hides the in-flight staging latency
    if (more) {
      if constexpr (!ABF16) writeA(cur ^ 1, va);   // write-late (loads landed under MFMA)
      __syncthreads();               // single barrier per K-step
    }
  }

  // --- epilogue 1: fused alpha dot products from fp32 acc ---
  {
    float asv[4], adv[4];
#pragma unroll
    for (int j = 0; j < 4; j++) {
      const int c = n0 + wn + j * 16 + lm;
      asv[j] = a_s[c];
      adv[j] = a_d[c];
    }
#pragma unroll
    for (int i = 0; i < 4; i++)
#pragma unroll
      for (int r = 0; r < 4; r++) {
        float ss = 0.f, dd = 0.f;
#pragma unroll
        for (int j = 0; j < 4; j++) {
          ss += acc[i][j][r] * asv[j];
          dd += acc[i][j][r] * adv[j];
        }
#pragma unroll
        for (int off = 1; off < 16; off <<= 1) {
          ss += __shfl_xor(ss, off);
          dd += __shfl_xor(dd, off);
        }
        if (lm == 0) {
          const int row = bm + wm + i * 16 + quad * 4 + r;
          if (row < M) {
            atomicAdd(&as_g[row], ss);
            atomicAdd(&ad_g[row], dd);
          }
        }
      }
  }

  // --- epilogue 2: C write, bf16 RNE; C/D layout col=lane&15, row=quad*4+reg ---
#pragma unroll
  for (int i = 0; i < 4; i++) {
    const int rbase = bm + wm + i * 16 + quad * 4;
#pragma unroll
    for (int j = 0; j < 4; j++) {
      const int c = n0 + wn + j * 16 + lm;
#pragma unroll
      for (int r = 0; r < 4; r++) {
        const int row = rbase + r;
        if (row < M) C[(size_t)row * Nn + c] = f2b_rne(acc[i][j][r]);
      }
    }
  }
}

// ---------------- fused single-pass edge softmax + aggregate + bias (+relu) ----------------
// WPN waves per dst node, each owning COLS=F/WPN columns -> G=512/COLS edges in flight.
// 2-deep pipeline: src index loaded 2 groups ahead, h-row/as_ 1 group ahead, so gather
// latency spans a full iteration of compute. Exact defer-max rescale.

template <int F, int WPN, bool OUTBF16, bool SWZ>
__global__ __launch_bounds__(256) void agg_fused(const unsigned short* __restrict__ h,
                                                 const float* __restrict__ as_,
                                                 const float* __restrict__ ad_,
                                                 const int* __restrict__ rowstart,
                                                 const int* __restrict__ csr_src,
                                                 const float* __restrict__ bias,
                                                 void* __restrict__ out,
                                                 int N, int do_relu) {
  constexpr int COLS = F / WPN;
  constexpr int LPR = COLS / 8;   // lanes per row slice
  constexpr int G = 64 / LPR;     // edges in flight per wave-iteration
  int wid = (blockIdx.x * 256 + threadIdx.x) >> 6;
  int lane = threadIdx.x & 63;
  int node = wid / WPN;
  int part = wid % WPN;
  if (node >= N) return;
  int r0 = rowstart[node], r1 = rowstart[node + 1];
  float adn = ad_[node];
  const int slot = lane / LPR;
  const int cpos = part * COLS + (lane % LPR) * 8;

  float m = -1e30f, ssum = 0.f;
  float acc[8];
#pragma unroll
  for (int v = 0; v < 8; v++) acc[v] = 0.f;

  // pipeline warm-up: group0's row/av resident, group1's src index in flight
  int idx = r0 + slot;
  bool okc = idx < r1;
  int s_c = csr_src[okc ? idx : r0];
  float avc = as_[s_c];
  ushort8 rowc = *(const ushort8*)(h + (size_t)s_c * F + cpos);
  idx += G;
  bool okn = idx < r1;
  int s_n = csr_src[okn ? idx : r0];

  for (int k = r0; k < r1; k += G) {
    // issue next group's gathers (s_n already resident) + next-next src index
    float avn = as_[s_n];
    ushort8 rown = *(const ushort8*)(h + (size_t)s_n * F + cpos);
    idx += G;
    bool ok2 = idx < r1;
    int s_2 = csr_src[ok2 ? idx : r0];

    float e = okc ? leaky(avc + adn) : -1e30f;
    if (!__all(e <= m)) {           // exact defer: rescale only on a new max somewhere
      float mn = fmaxf(m, e);
      float sc = __expf(m - mn);
      ssum *= sc;
#pragma unroll
      for (int v = 0; v < 8; v++) acc[v] *= sc;
      m = mn;
    }
    float wgt = okc ? __expf(e - m) : 0.f;
    ssum += wgt;
#pragma unroll
    for (int v = 0; v < 8; v++) acc[v] += wgt * b2f(rowc[v]);

    okc = okn; avc = avn; rowc = rown;
    okn = ok2; s_n = s_2;
  }

  // merge slots: online-softmax merge across lane groups
#pragma unroll
  for (int off = LPR; off < 64; off <<= 1) {
    float mo = __shfl_xor(m, off);
    float so = __shfl_xor(ssum, off);
    float ao[8];
#pragma unroll
    for (int v = 0; v < 8; v++) ao[v] = __shfl_xor(acc[v], off);
    float mn = fmaxf(m, mo);
    float sa = __expf(m - mn), sb = __expf(mo - mn);
    ssum = ssum * sa + so * sb;
#pragma unroll
    for (int v = 0; v < 8; v++) acc[v] = acc[v] * sa + ao[v] * sb;
    m = mn;
  }

  if (lane < LPR) {
    float inv = 1.f / ssum;   // self-loop guarantees ssum > 0
    float o[8];
#pragma unroll
    for (int v = 0; v < 8; v++) {
      float x = acc[v] * inv + bias[cpos + v];
      if (do_relu) x = fmaxf(x, 0.f);
      o[v] = x;
    }
    if (OUTBF16) {
      unsigned short u[8];
#pragma unroll
      for (int v = 0; v < 8; v++) u[v] = f2b_rne(o[v]);
      int cdst = SWZ ? ((cpos & ~31) | (swz_unit((cpos >> 3) & 3, node) << 3)) : cpos;
      *(ushort8*)((unsigned short*)out + (size_t)node * F + cdst) = *(ushort8*)u;
    } else {
      float* op = (float*)out + (size_t)node * F + cpos;
      *(f32x4*)op = *(f32x4*)&o[0];
      *(f32x4*)(op + 4) = *(f32x4*)&o[4];
    }
  }
}

// ---------------- layer 3: GEMM (K x 2) + alpha3, wave per row (f32x4 loads) ----------------

__global__ __launch_bounds__(256) void gemm3_kernel(const float* __restrict__ h,
                                                    const float* __restrict__ W3,
                                                    const float* __restrict__ a3s,
                                                    const float* __restrict__ a3d,
                                                    float* __restrict__ h3,
                                                    float* __restrict__ as_,
                                                    float* __restrict__ ad_,
                                                    int N, int K) {
  int wid = (blockIdx.x * 256 + threadIdx.x) >> 6;
  int lane = threadIdx.x & 63;
  if (wid >= N) return;
  float c0 = 0.f, c1 = 0.f;
  const float* hp = h + (int64_t)wid * K;
  for (int k = lane * 4; k < K; k += 256) {
    f32x4 v = *(const f32x4*)(hp + k);
#pragma unroll
    for (int j = 0; j < 4; j++) {
      c0 += v[j] * W3[(k + j) * 2 + 0];
      c1 += v[j] * W3[(k + j) * 2 + 1];
    }
  }
#pragma unroll
  for (int off = 32; off; off >>= 1) {
    c0 += __shfl_down(c0, off);
    c1 += __shfl_down(c1, off);
  }
  if (lane == 0) {
    h3[wid * 2 + 0] = c0;
    h3[wid * 2 + 1] = c1;
    as_[wid] = c0 * a3s[0] + c1 * a3s[1];
    ad_[wid] = c0 * a3d[0] + c1 * a3d[1];
  }
}

// ---------------- layer 3: single-pass online aggregate + bias + 2-class softmax ----------------

__global__ __launch_bounds__(256) void agg3_kernel(const float* __restrict__ h3,
                                                   const float* __restrict__ as_,
                                                   const float* __restrict__ ad_,
                                                   const int* __restrict__ rowstart,
                                                   const int* __restrict__ csr_src,
                                                   const float* __restrict__ b3,
                                                   float* __restrict__ out, int N) {
  int wid = (blockIdx.x * 256 + threadIdx.x) >> 6;
  int lane = threadIdx.x & 63;
  if (wid >= N) return;
  int r0 = rowstart[wid], r1 = rowstart[wid + 1];
  float adn = ad_[wid];

  float m = -1e30f, ssum = 0.f, a0 = 0.f, a1 = 0.f;
  for (int i = r0 + lane; i < r1; i += 64) {
    int s = csr_src[i];
    float e = leaky(as_[s] + adn);
    f32x2 hv = *(const f32x2*)(h3 + 2 * (int64_t)s);
    if (!__all(e <= m)) {
      float mn = fmaxf(m, e);
      float sc = __expf(m - mn);
      ssum *= sc; a0 *= sc; a1 *= sc;
      m = mn;
    }
    float w = __expf(e - m);
    ssum += w;
    a0 += w * hv[0];
    a1 += w * hv[1];
  }
#pragma unroll
  for (int off = 32; off; off >>= 1) {
    float mo = __shfl_xor(m, off);
    float so = __shfl_xor(ssum, off);
    float b0 = __shfl_xor(a0, off);
    float b1 = __shfl_xor(a1, off);
    float mn = fmaxf(m, mo);
    float sa = __expf(m - mn), sb = __expf(mo - mn);
    ssum = ssum * sa + so * sb;
    a0 = a0 * sa + b0 * sb;
    a1 = a1 * sa + b1 * sb;
    m = mn;
  }
  if (lane == 0) {
    float inv = 1.f / ssum;
    float o0 = a0 * inv + b3[0];
    float o1 = a1 * inv + b3[1];
    float mm = fmaxf(o0, o1);
    float e0 = __expf(o0 - mm), e1 = __expf(o1 - mm);
    float d = e0 + e1;
    out[wid * 2 + 0] = e0 / d;
    out[wid * 2 + 1] = e1 / d;
  }
}

// ---------------- launcher ----------------

extern "C" void kernel_launch(void* const* d_in, const int* in_sizes, int n_in,
                              void* d_out, int out_size, void* d_ws, size_t ws_size,
                              hipStream_t stream) {
  const float* x   = (const float*)d_in[0];
  const int*   ei  = (const int*)d_in[1];
  const float* W1  = (const float*)d_in[3];
  const float* a1s = (const float*)d_in[4];
  const float* a1d = (const float*)d_in[5];
  const float* b1  = (const float*)d_in[6];
  const float* W2  = (const float*)d_in[7];
  const float* a2s = (const float*)d_in[8];
  const float* a2d = (const float*)d_in[9];
  const float* b2  = (const float*)d_in[10];
  const float* W3  = (const float*)d_in[11];
  const float* a3s = (const float*)d_in[12];
  const float* a3d = (const float*)d_in[13];
  const float* b3  = (const float*)d_in[14];

  int N   = in_sizes[2];
  int E   = in_sizes[1] / 2;
  int FIN = in_sizes[0] / N;    // 784
  int d1  = in_sizes[4];        // 128
  int d2  = in_sizes[8];        // 256
  int Kp1 = ((FIN + 31) / 32) * 32;  // 800

  // workspace carve
  char* p = (char*)d_ws;
  unsigned short* hbuf = (unsigned short*)p; p += (size_t)N * d2 * sizeof(float);
  float* buf2 = (float*)p; p += (size_t)N * d2 * sizeof(float);
  float* h3   = (float*)p; p += (size_t)N * 2 * sizeof(float);
  float* as_  = (float*)p; p += (size_t)N * sizeof(float);
  float* ad_  = (float*)p; p += (size_t)N * sizeof(float);   // contiguous after as_
  int* deg      = (int*)p; p += (size_t)N * sizeof(int);
  int* rowstart = (int*)p; p += (size_t)(N + 1) * sizeof(int);
  int* bsum     = (int*)p; p += 1024 * sizeof(int);
  int* rank     = (int*)p; p += (size_t)(E + N) * sizeof(int);
  int* csr      = (int*)p; p += (size_t)(E + N) * sizeof(int);
  p = (char*)(((uintptr_t)p + 255) & ~(uintptr_t)255);
  short* w1h = (short*)p; p += (size_t)d1 * Kp1 * sizeof(short);
  short* w1l = (short*)p; p += (size_t)d1 * Kp1 * sizeof(short);
  short* w2h = (short*)p; p += (size_t)d2 * d1 * sizeof(short);
  short* w2l = (short*)p; p += (size_t)d2 * d1 * sizeof(short);
  p = (char*)(((uintptr_t)p + 255) & ~(uintptr_t)255);
  // +128 row slack: GEMM2's unpredicated global_load_lds reads past row N in the last tile
  short* h1b = (short*)p; p += (size_t)(N + 128) * d1 * sizeof(short);

  // CSR build (multi-block scan; nb<=256 requires N<=262144)
  hipMemsetAsync(deg, 0, (size_t)N * sizeof(int), stream);
  int tot = E + N;
  hist_kernel<<<(tot + 255) / 256, 256, 0, stream>>>(ei, deg, rank, E, N);
  int nb = (N + 1023) / 1024;
  scan_phaseA<<<nb, 256, 0, stream>>>(deg, bsum, N);
  scan_phaseB<<<1, 256, 0, stream>>>(bsum, rowstart, nb, N);
  scan_phaseC<<<nb, 256, 0, stream>>>(deg, bsum, rowstart, N);
  scatter_kernel<<<(tot + 255) / 256, 256, 0, stream>>>(ei, rowstart, rank, csr, E, N);

  // weight transpose+split+swizzle, both layers in one launch (tiny)
  int cw_tot = d1 * Kp1 + d2 * d1;
  convw2_kernel<<<(cw_tot + 255) / 256, 256, 0, stream>>>(W1, w1h, w1l, FIN, d1, Kp1,
                                                          W2, w2h, w2l, d1, d2, d1);

  int wb2 = (2 * N + 3) / 4;  // 2 waves per node, 4 waves/block

  // layer 1: x@W1 -> hbuf bf16 [N,128] + fused alpha; agg -> h1b bf16 swizzled (relu)
  {
    hipMemsetAsync(as_, 0, (size_t)2 * N * sizeof(float), stream);  // as_ + ad_ (contiguous)
    dim3 g((N + 127) / 128, d1 / 128);
    mfma_gemm_split<false><<<g, 256, 0, stream>>>(x, nullptr, w1h, w1l, hbuf,
                                                  a1s, a1d, as_, ad_, N, d1, FIN, Kp1);
    agg_fused<128, 2, true, true><<<wb2, 256, 0, stream>>>(hbuf, as_, ad_, rowstart, csr, b1, h1b, N, 1);
  }
  // layer 2: h1b(bf16,swz)@W2 -> hbuf bf16 [N,256] + fused alpha; agg -> buf2 fp32 (relu)
  {
    hipMemsetAsync(as_, 0, (size_t)2 * N * sizeof(float), stream);
    dim3 g((N + 127) / 128, d2 / 128);
    mfma_gemm_split<true><<<g, 256, 0, stream>>>(nullptr, h1b, w2h, w2l, hbuf,
                                                 a2s, a2d, as_, ad_, N, d2, d1, d1);
    agg_fused<256, 2, false, false><<<wb2, 256, 0, stream>>>(hbuf, as_, ad_, rowstart, csr, b2, buf2, N, 1);
  }
  // layer 3: buf2@W3 -> h3 [N,2]; single-pass agg + bias + softmax -> d_out
  {
    int wb = (N + 3) / 4;
    gemm3_kernel<<<wb, 256, 0, stream>>>(buf2, W3, a3s, a3d, h3, as_, ad_, N, d2);
    agg3_kernel<<<wb, 256, 0, stream>>>(h3, as_, ad_, rowstart, csr, b3, (float*)d_out, N);
  }
}